// Round 1
// baseline (13094.406 us; speedup 1.0000x reference)
//
#include <hip/hip_runtime.h>
#include <cstdint>
#include <cstddef>

// GRU-D: B=64, T=512, D=256, H=1024.
// v1 strategy: correctness + baseline. f16 storage / v_dot2_f32_f16 compute,
// fp32 accumulate. Multi-kernel scan (2 kernels per time step) — no grid
// barriers yet; per-step sync comes free from stream ordering.

#define NB 64
#define NT 512
#define ND 256
#define NH 1024

typedef _Float16 h2_t __attribute__((ext_vector_type(2)));

__device__ __forceinline__ float fdot2(uint32_t a, uint32_t b, float acc) {
  h2_t ha = __builtin_bit_cast(h2_t, a);
  h2_t hb = __builtin_bit_cast(h2_t, b);
#if __has_builtin(__builtin_amdgcn_fdot2)
  return __builtin_amdgcn_fdot2(ha, hb, acc, false);
#else
  return acc + (float)ha[0] * (float)hb[0] + (float)ha[1] * (float)hb[1];
#endif
}

__device__ __forceinline__ uint32_t pack2(float a, float b) {
  h2_t v; v[0] = (_Float16)a; v[1] = (_Float16)b;
  return __builtin_bit_cast(uint32_t, v);
}
__device__ __forceinline__ uint16_t f2h(float x) {
  _Float16 v = (_Float16)x; return __builtin_bit_cast(uint16_t, v);
}
__device__ __forceinline__ float h2f(uint16_t u) {
  return (float)__builtin_bit_cast(_Float16, u);
}

// ---- pack kernels ------------------------------------------------------

// x [32768][256] f32 -> x2 [32768][128] f16x2 (pairs along D)
__global__ void pack_x_k(const float2* __restrict__ x, uint32_t* __restrict__ x2, int n) {
  int stride = gridDim.x * blockDim.x;
  for (int i = blockIdx.x * blockDim.x + threadIdx.x; i < n; i += stride) {
    float2 v = x[i];
    x2[i] = pack2(v.x, v.y);
  }
}

// src [K][1024] f32 -> dst [K/2][1024] f16x2 (pairs along K)
__global__ void pack_rows_k(const float* __restrict__ src, uint32_t* __restrict__ dst, int K) {
  int n = (K >> 1) * NH;
  int stride = gridDim.x * blockDim.x;
  for (int i = blockIdx.x * blockDim.x + threadIdx.x; i < n; i += stride) {
    int kp = i >> 10, j = i & 1023;
    dst[i] = pack2(src[(2 * kp) * NH + j], src[(2 * kp + 1) * NH + j]);
  }
}

// ---- phase 1: input projections ---------------------------------------
// out[n, c] = x[n,:] @ Wcat[:, c] + bias; c in [0,4096): a = c>>10 selects
// {Wd->gamma, Wz->xz, Wr->xr, Wh->xh}. gamma = exp(-relu(.)).
// Tile: [64 rows x 64 cols], K=256 (128 f16-pairs). grid = 512*64 WGs.
__global__ __launch_bounds__(256) void proj_k(
    const uint32_t* __restrict__ x2, const uint32_t* __restrict__ W2,
    const float* __restrict__ bd, const float* __restrict__ bz,
    const float* __restrict__ br, const float* __restrict__ bh,
    uint16_t* __restrict__ g_gamma, uint16_t* __restrict__ g_xz,
    uint16_t* __restrict__ g_xr, uint16_t* __restrict__ g_xh) {
  __shared__ uint32_t xs[64 * 132];  // pad 128->132 dwords to spread banks
  int wg = blockIdx.x;
  int rg = wg >> 6;   // row group [0,512)
  int cg = wg & 63;   // col group [0,64)
  int tid = threadIdx.x;

  // stage x2 rows [rg*64, +64): 2048 uint4
  const uint4* xsrc = (const uint4*)x2 + (size_t)rg * 64 * 32;
#pragma unroll
  for (int w = 0; w < 8; ++w) {
    int f = tid + w * 256;
    int row = f >> 5, q = f & 31;
    *(uint4*)&xs[row * 132 + q * 4] = xsrc[row * 32 + q];
  }
  __syncthreads();

  int a = cg >> 4;
  int j0 = (cg & 15) * 64 + (tid & 15) * 4;  // col within 1024
  int tr = tid >> 4;
  const uint32_t* W2a = W2 + (size_t)a * (128 * 1024) + j0;

  float acc[4][4] = {};
#pragma unroll 4
  for (int kp = 0; kp < 128; ++kp) {
    uint32_t xv0 = xs[(tr * 4 + 0) * 132 + kp];
    uint32_t xv1 = xs[(tr * 4 + 1) * 132 + kp];
    uint32_t xv2 = xs[(tr * 4 + 2) * 132 + kp];
    uint32_t xv3 = xs[(tr * 4 + 3) * 132 + kp];
    uint4 wv = *(const uint4*)(W2a + (size_t)kp * 1024);
    acc[0][0] = fdot2(xv0, wv.x, acc[0][0]); acc[0][1] = fdot2(xv0, wv.y, acc[0][1]);
    acc[0][2] = fdot2(xv0, wv.z, acc[0][2]); acc[0][3] = fdot2(xv0, wv.w, acc[0][3]);
    acc[1][0] = fdot2(xv1, wv.x, acc[1][0]); acc[1][1] = fdot2(xv1, wv.y, acc[1][1]);
    acc[1][2] = fdot2(xv1, wv.z, acc[1][2]); acc[1][3] = fdot2(xv1, wv.w, acc[1][3]);
    acc[2][0] = fdot2(xv2, wv.x, acc[2][0]); acc[2][1] = fdot2(xv2, wv.y, acc[2][1]);
    acc[2][2] = fdot2(xv2, wv.z, acc[2][2]); acc[2][3] = fdot2(xv2, wv.w, acc[2][3]);
    acc[3][0] = fdot2(xv3, wv.x, acc[3][0]); acc[3][1] = fdot2(xv3, wv.y, acc[3][1]);
    acc[3][2] = fdot2(xv3, wv.z, acc[3][2]); acc[3][3] = fdot2(xv3, wv.w, acc[3][3]);
  }

  const float* bias = a == 0 ? bd : a == 1 ? bz : a == 2 ? br : bh;
  uint16_t* dst = a == 0 ? g_gamma : a == 1 ? g_xz : a == 2 ? g_xr : g_xh;
  float b0 = bias[j0], b1 = bias[j0 + 1], b2 = bias[j0 + 2], b3 = bias[j0 + 3];
#pragma unroll
  for (int i = 0; i < 4; ++i) {
    int n = rg * 64 + tr * 4 + i;
    int b = n >> 9, t = n & 511;
    float p0 = acc[i][0] + b0, p1 = acc[i][1] + b1;
    float p2 = acc[i][2] + b2, p3 = acc[i][3] + b3;
    if (a == 0) {
      p0 = __expf(-fmaxf(p0, 0.f)); p1 = __expf(-fmaxf(p1, 0.f));
      p2 = __expf(-fmaxf(p2, 0.f)); p3 = __expf(-fmaxf(p3, 0.f));
    }
    uint32_t* o = (uint32_t*)(dst + (((size_t)(t * 64 + b)) << 10) + j0);
    o[0] = pack2(p0, p1);
    o[1] = pack2(p2, p3);
  }
}

// ---- phase 2 step A: z and r gates ------------------------------------
// Output [64 x 2048] ([Uz | Ur]); tile [16 b x 32 c]; grid 4*64 = 256 WGs.
// a==0: Z = sigmoid(xz + hdec@Uz); a==1: RH = sigmoid(xr + hdec@Ur) * hdec.
__global__ __launch_bounds__(256) void stepA_k(
    const uint32_t* __restrict__ hdec2, const uint32_t* __restrict__ U2,
    const uint16_t* __restrict__ g_xz, const uint16_t* __restrict__ g_xr,
    const uint16_t* __restrict__ hdec_h,
    uint16_t* __restrict__ Z, uint16_t* __restrict__ RH, int t) {
  __shared__ uint32_t hs[16 * 512];
  int wg = blockIdx.x;
  int bg = wg >> 6;   // [0,4)
  int cg = wg & 63;   // [0,64): cols C0 = cg*32 in [0,2048)
  int tid = threadIdx.x;

  const uint4* hsrc = (const uint4*)hdec2 + (size_t)bg * 16 * 128;
#pragma unroll
  for (int w = 0; w < 8; ++w) {
    int f = tid + w * 256;
    *(uint4*)&hs[f * 4] = hsrc[f];
  }
  __syncthreads();

  int C0 = cg * 32;
  int a = C0 >> 10;                    // 0 = z, 1 = r
  int j = (C0 & 1023) + (tid & 31);
  int tq = tid >> 5;                   // [0,8) -> 2 rows each
  int r0 = 2 * tq, r1 = 2 * tq + 1;
  const uint32_t* Ua = U2 + (size_t)a * (512 * 1024) + j;

  float a0 = 0.f, a1 = 0.f;
#pragma unroll 16
  for (int kp = 0; kp < 512; ++kp) {
    uint32_t u = Ua[(size_t)kp * 1024];
    a0 = fdot2(hs[r0 * 512 + kp], u, a0);
    a1 = fdot2(hs[r1 * 512 + kp], u, a1);
  }

  int gb0 = bg * 16 + r0, gb1 = bg * 16 + r1;
  const uint16_t* xg = (a == 0 ? g_xz : g_xr);
  size_t tb0 = (((size_t)(t * 64 + gb0)) << 10) + j;
  size_t tb1 = (((size_t)(t * 64 + gb1)) << 10) + j;
  float s0 = 1.f / (1.f + __expf(-(h2f(xg[tb0]) + a0)));
  float s1 = 1.f / (1.f + __expf(-(h2f(xg[tb1]) + a1)));
  if (a == 0) {
    Z[(gb0 << 10) + j] = f2h(s0);
    Z[(gb1 << 10) + j] = f2h(s1);
  } else {
    float hd0 = h2f(hdec_h[(gb0 << 10) + j]);
    float hd1 = h2f(hdec_h[(gb1 << 10) + j]);
    RH[(gb0 << 10) + j] = f2h(s0 * hd0);
    RH[(gb1 << 10) + j] = f2h(s1 * hd1);
  }
}

// ---- phase 2 step B: candidate + combine ------------------------------
// Output [64 x 1024]; tile [16 b x 16 c]; grid 4*64 = 256 WGs.
__global__ __launch_bounds__(256) void stepB_k(
    const uint32_t* __restrict__ RH2, const uint32_t* __restrict__ U2,
    const uint16_t* __restrict__ g_xh, const uint16_t* __restrict__ g_gamma,
    const uint16_t* __restrict__ Z, uint16_t* __restrict__ hdec_h,
    float* __restrict__ out, int t) {
  __shared__ uint32_t rs[16 * 520];  // pad 512->520 dwords: 4 rows/wave -> 4 banks
  int wg = blockIdx.x;
  int bg = wg >> 6, cg = wg & 63;
  int tid = threadIdx.x;

  const uint4* rsrc = (const uint4*)RH2 + (size_t)bg * 16 * 128;
#pragma unroll
  for (int w = 0; w < 8; ++w) {
    int f = tid + w * 256;
    int row = f >> 7, q = f & 127;
    *(uint4*)&rs[row * 520 + q * 4] = rsrc[f];
  }
  __syncthreads();

  int tc = tid & 15, tq = tid >> 4;
  int j = cg * 16 + tc;
  int r = bg * 16 + tq;
  const uint32_t* Uh2 = U2 + (size_t)2 * (512 * 1024) + j;

  float acc = 0.f;
#pragma unroll 16
  for (int kp = 0; kp < 512; ++kp)
    acc = fdot2(rs[tq * 520 + kp], Uh2[(size_t)kp * 1024], acc);

  size_t tb = (((size_t)(t * 64 + r)) << 10) + j;
  float hp = tanhf(h2f(g_xh[tb]) + acc);
  float zf = h2f(Z[(r << 10) + j]);
  float hd = h2f(hdec_h[(r << 10) + j]);
  float h = (1.f - zf) * hd + zf * hp;
  out[((size_t)r * NT + t) * NH + j] = h;
  if (t + 1 < NT) {
    float g = h2f(g_gamma[(((size_t)((t + 1) * 64 + r)) << 10) + j]);
    hdec_h[(r << 10) + j] = f2h(g * h);
  }
}

// ---- launch ------------------------------------------------------------

extern "C" void kernel_launch(void* const* d_in, const int* in_sizes, int n_in,
                              void* d_out, int out_size, void* d_ws, size_t ws_size,
                              hipStream_t stream) {
  const float* x  = (const float*)d_in[0];
  const float* Wd = (const float*)d_in[1];
  const float* bd = (const float*)d_in[2];
  const float* Wz = (const float*)d_in[3];
  const float* Wr = (const float*)d_in[4];
  const float* Wh = (const float*)d_in[5];
  const float* Uz = (const float*)d_in[6];
  const float* Ur = (const float*)d_in[7];
  const float* Uh = (const float*)d_in[8];
  const float* bz = (const float*)d_in[9];
  const float* br = (const float*)d_in[10];
  const float* bh = (const float*)d_in[11];
  float* out = (float*)d_out;

  char* ws = (char*)d_ws;
  size_t off = 0;
  auto take = [&](size_t bytes) -> char* {
    char* p = ws + off;
    off = (off + bytes + 255) & ~(size_t)255;
    return p;
  };
  uint32_t* x2 = (uint32_t*)take((size_t)32768 * 128 * 4);   // 16 MiB
  uint32_t* W2 = (uint32_t*)take((size_t)4 * 128 * 1024 * 4); // 2 MiB
  uint32_t* U2 = (uint32_t*)take((size_t)3 * 512 * 1024 * 4); // 6 MiB
  uint16_t* g_gamma = (uint16_t*)take((size_t)NT * NB * NH * 2); // 64 MiB
  uint16_t* g_xz   = (uint16_t*)take((size_t)NT * NB * NH * 2);
  uint16_t* g_xr   = (uint16_t*)take((size_t)NT * NB * NH * 2);
  uint16_t* g_xh   = (uint16_t*)take((size_t)NT * NB * NH * 2);
  uint16_t* hdec   = (uint16_t*)take((size_t)NB * NH * 2);
  uint16_t* Zb     = (uint16_t*)take((size_t)NB * NH * 2);
  uint16_t* RHb    = (uint16_t*)take((size_t)NB * NH * 2);
  (void)ws_size; (void)in_sizes; (void)n_in; (void)out_size;

  hipMemsetAsync(hdec, 0, (size_t)NB * NH * 2, stream);

  pack_x_k<<<2048, 256, 0, stream>>>((const float2*)x, x2, 32768 * 128);
  pack_rows_k<<<512, 256, 0, stream>>>(Wd, W2 + 0 * (128 * 1024), ND);
  pack_rows_k<<<512, 256, 0, stream>>>(Wz, W2 + 1 * (128 * 1024), ND);
  pack_rows_k<<<512, 256, 0, stream>>>(Wr, W2 + 2 * (128 * 1024), ND);
  pack_rows_k<<<512, 256, 0, stream>>>(Wh, W2 + 3 * (128 * 1024), ND);
  pack_rows_k<<<2048, 256, 0, stream>>>(Uz, U2 + (size_t)0 * (512 * 1024), NH);
  pack_rows_k<<<2048, 256, 0, stream>>>(Ur, U2 + (size_t)1 * (512 * 1024), NH);
  pack_rows_k<<<2048, 256, 0, stream>>>(Uh, U2 + (size_t)2 * (512 * 1024), NH);

  proj_k<<<32768, 256, 0, stream>>>(x2, W2, bd, bz, br, bh,
                                    g_gamma, g_xz, g_xr, g_xh);

  for (int t = 0; t < NT; ++t) {
    stepA_k<<<256, 256, 0, stream>>>((const uint32_t*)hdec, U2, g_xz, g_xr,
                                     hdec, Zb, RHb, t);
    stepB_k<<<256, 256, 0, stream>>>((const uint32_t*)RHb, U2, g_xh, g_gamma,
                                     Zb, hdec, out, t);
  }
}